// Round 9
// baseline (544.143 us; speedup 1.0000x reference)
//
#include <hip/hip_runtime.h>
#include <stdint.h>

#define HOR 128
#define NPATH 4096
#define BATCH 8
#define DM 512
#define H 64
#define BN (BATCH*NPATH)

typedef __attribute__((ext_vector_type(8))) short s16x8;   // 8 bf16 = 4 VGPRs
typedef __attribute__((ext_vector_type(4))) float f32x4;   // MFMA C/D

// ---------------- threefry2x32 (JAX-exact) ----------------
__device__ __forceinline__ uint32_t rotl32(uint32_t x, int r) {
  return (x << r) | (x >> (32 - r));
}

__device__ __forceinline__ void tf2x32(uint32_t k0, uint32_t k1,
                                       uint32_t& x0, uint32_t& x1) {
  uint32_t k2 = k0 ^ k1 ^ 0x1BD11BDAu;
  x0 += k0; x1 += k1;
#define TFR4(a,b,c,d) \
  x0 += x1; x1 = rotl32(x1,a); x1 ^= x0; \
  x0 += x1; x1 = rotl32(x1,b); x1 ^= x0; \
  x0 += x1; x1 = rotl32(x1,c); x1 ^= x0; \
  x0 += x1; x1 = rotl32(x1,d); x1 ^= x0;
  TFR4(13,15,26,6)  x0 += k1; x1 += k2 + 1u;
  TFR4(17,29,16,24) x0 += k2; x1 += k0 + 2u;
  TFR4(13,15,26,6)  x0 += k0; x1 += k1 + 3u;
  TFR4(17,29,16,24) x0 += k1; x1 += k2 + 4u;
  TFR4(13,15,26,6)  x0 += k2; x1 += k0 + 5u;
#undef TFR4
}

// ---------------- math helpers ----------------
__device__ __forceinline__ float rcpf(float x) { return __builtin_amdgcn_rcpf(x); }
__device__ __forceinline__ float siluf(float x) {
  return x * rcpf(1.0f + __expf(-x));
}
__device__ __forceinline__ float softplusf(float x) {     // k_pre only (unchanged)
  return fmaxf(x, 0.0f) + log1pf(__expf(-fabsf(x)));
}
// in-loop softplus: z = e^-|x| in (0,1] -> 1+z in (1,2], v_log ~1ulp there.
// kills the serial log1pf libm tail (~40-60cy) on the per-step critical path.
__device__ __forceinline__ float softplus_fast(float x) {
  return fmaxf(x, 0.0f) + __logf(1.0f + __expf(-fabsf(x)));
}

__device__ __forceinline__ float bits_to_normal(uint32_t bits) {
  uint32_t fb = (bits >> 9) | 0x3F800000u;
  float f = __uint_as_float(fb) - 1.0f;
  float u = fmaf(f, 2.0f, -0.99999994f);
  u = fmaxf(u, -0.99999994f);
  float w = -log1pf(-u * u);
  float p;
  if (w < 5.0f) {
    w = w - 2.5f;
    p = 2.81022636e-08f;
    p = fmaf(p, w, 3.43273939e-07f);
    p = fmaf(p, w, -3.5233877e-06f);
    p = fmaf(p, w, -4.39150654e-06f);
    p = fmaf(p, w, 0.00021858087f);
    p = fmaf(p, w, -0.00125372503f);
    p = fmaf(p, w, -0.00417768164f);
    p = fmaf(p, w, 0.246640727f);
    p = fmaf(p, w, 1.50140941f);
  } else {
    w = sqrtf(w) - 3.0f;
    p = -0.000200214257f;
    p = fmaf(p, w, 0.000100950558f);
    p = fmaf(p, w, 0.00134934322f);
    p = fmaf(p, w, -0.00367342844f);
    p = fmaf(p, w, 0.00573950773f);
    p = fmaf(p, w, -0.0076224613f);
    p = fmaf(p, w, 0.00943887047f);
    p = fmaf(p, w, 1.00167406f);
    p = fmaf(p, w, 2.83297682f);
  }
  return 1.41421356237f * (p * u);
}

// pack top-16 bits of two fp32 -> one dword of 2 bf16 (truncation round)
__device__ __forceinline__ uint32_t pack_hi16(uint32_t hi_src, uint32_t lo_src) {
  return __builtin_amdgcn_perm(hi_src, lo_src, 0x07060302u);
}

union FragU { uint32_t u[4]; s16x8 v; };

// split 8 fp32 -> 3 bf16x8 fragments: x = hi + mid + lo + O(2^-24 |x|)
__device__ __forceinline__ void split3(const float (&x)[8],
                                       s16x8& fh, s16x8& fm, s16x8& fl) {
  FragU Hh, Mm, Ll;
  #pragma unroll
  for (int d = 0; d < 4; ++d) {
    float x0 = x[2*d], x1 = x[2*d+1];
    uint32_t a0 = __float_as_uint(x0), a1 = __float_as_uint(x1);
    float r10 = x0 - __uint_as_float(a0 & 0xFFFF0000u);
    float r11 = x1 - __uint_as_float(a1 & 0xFFFF0000u);
    uint32_t m0 = __float_as_uint(r10), m1 = __float_as_uint(r11);
    float r20 = r10 - __uint_as_float(m0 & 0xFFFF0000u);
    float r21 = r11 - __uint_as_float(m1 & 0xFFFF0000u);
    Hh.u[d] = pack_hi16(a1, a0);
    Mm.u[d] = pack_hi16(m1, m0);
    Ll.u[d] = pack_hi16(__float_as_uint(r21), __float_as_uint(r20));
  }
  fh = Hh.v; fm = Mm.v; fl = Ll.v;
}

#define MFMA16(A, B, C) __builtin_amdgcn_mfma_f32_16x16x32_bf16((A), (B), (C), 0, 0, 0)

// ws layout (floats): [0,512) base_f1[b][j], [512,1024) base_g1[b][j],
// (u32 view) [1024,1152) keyA[t], [1152,1280) keyB[t]

__global__ void k_pre(const float* __restrict__ h_t,
                      const float* __restrict__ W_f1, const float* __restrict__ b_f1,
                      const float* __restrict__ W_g1, const float* __restrict__ b_g1,
                      const float* __restrict__ W_mu, const float* __restrict__ b_mu,
                      const float* __restrict__ W_sig, const float* __restrict__ b_sig,
                      float* __restrict__ out, float* __restrict__ ws) {
  int j = threadIdx.x;           // 0..63
  int b = blockIdx.x;
  if (b == 8) {
    uint32_t* keyA = (uint32_t*)ws + 1024;
    uint32_t* keyB = (uint32_t*)ws + 1152;
    for (int t = j; t < HOR; t += 64) {
      uint32_t x0 = 0u, x1 = (uint32_t)t;
      tf2x32(0u, 42u, x0, x1);
      keyA[t] = x0; keyB[t] = x1;
    }
    return;
  }
  const float* h = h_t + b * DM;
  float accF = b_f1[j], accG = b_g1[j];
  float pm = 0.0f, ps = 0.0f;
  #pragma unroll 4
  for (int d = 0; d < DM; ++d) {
    float hv = h[d];
    accF = fmaf(hv, W_f1[d * H + j], accF);
    accG = fmaf(hv, W_g1[d * H + j], accG);
  }
  ws[b * H + j] = accF;
  ws[512 + b * H + j] = accG;
  for (int d = j; d < DM; d += 64) {
    pm = fmaf(h[d], W_mu[d], pm);
    ps = fmaf(h[d], W_sig[d], ps);
  }
  #pragma unroll
  for (int off = 32; off > 0; off >>= 1) {
    pm += __shfl_down(pm, off);
    ps += __shfl_down(ps, off);
  }
  if (j == 0) {
    out[BN * HOR + b] = pm + b_mu[0];
    out[BN * HOR + 8 + b] = softplusf(ps + b_sig[0]) + 1e-6f;
  }
}

// -----------------------------------------------------------------------------
// R9 = R8 (455.8us best) + per-step serial-tail cuts. R8 analysis: per-wave
// time pinned ~4300cy/step across R0/R8 (~60% dep-stall); at 2 waves/SIMD
// (grid-capped: 2048 waves / 1024 SIMDs) the only barrier-free lever is
// per-wave dependency depth:
//  1. fa/ga: 4x4 fma chains + 2-level tree (depth ~96cy -> ~35cy each).
//  2. in-loop softplus via __logf(1+z) (kills log1pf libm serial tail).
//  3. g-net split into two blocks interleaved between MFMA s-clusters
//     (independent VALU/trans to issue under the 24-MFMA stretches).
//  4. opaque-kg hack removed (let allocator hoist/demote g-weights itself).
// RNG path, h1/split3 math, MFMA term order: bit-identical to R8.
// Fallback (pre-committed): <2% gain -> j-split 1-barrier 4-wave structure.
// -----------------------------------------------------------------------------
__global__ __launch_bounds__(256, 2)
void k_sde(const float* __restrict__ ip,
           const float* __restrict__ W_f1, const float* __restrict__ W_f2,
           const float* __restrict__ b_f2, const float* __restrict__ W_f3,
           const float* __restrict__ b_f3, const float* __restrict__ W_g1,
           const float* __restrict__ W_g2, const float* __restrict__ b_g2,
           float* __restrict__ out, const float* __restrict__ ws) {
  __shared__ __align__(16) float sW2[H * H];          // prologue staging only
  __shared__ __align__(16) float sF1y[H], sF1t[H], sBF[H];
  __shared__ __align__(16) float sGy[H], sGt[H], sBG[H], sG2[H];
  __shared__ __align__(16) float sF3[H], sBf2[H];
  __shared__ uint32_t sKA[HOR], sKB[HOR];

  const int tid  = threadIdx.x;
  const int rblk = blockIdx.x * 64;       // 64 rows per block (4 waves x 16)
  const int b    = rblk >> 12;            // batch: uniform per block

  #pragma unroll
  for (int m = 0; m < 16; ++m) sW2[tid + 256 * m] = W_f2[tid + 256 * m];
  if (tid < 64) {
    sF1y[tid] = W_f1[512 * H + tid];
    sF1t[tid] = W_f1[513 * H + tid];
    sGy[tid]  = W_g1[512 * H + tid];
    sGt[tid]  = W_g1[513 * H + tid];
    sF3[tid]  = W_f3[tid];
    sG2[tid]  = W_g2[tid];
    sBf2[tid] = b_f2[tid];
  } else if (tid < 128) {
    int i = tid - 64;
    sBF[i] = ws[b * H + i];
    sBG[i] = ws[512 + b * H + i];
  } else {
    const uint32_t* kws = (const uint32_t*)ws;
    int t = tid - 128;
    sKA[t] = kws[1024 + t];
    sKB[t] = kws[1152 + t];
  }
  __syncthreads();

  const int l  = tid & 63;
  const int wv = tid >> 6;
  const int rl = l & 15;                  // row-local / D column / B column
  const int h  = l >> 4;                  // k-group quarter
  const int r  = rblk + wv * 16 + rl;     // global row

  // ---- static A fragments: W2^T, 3-way bf16 split (96 VGPRs) ----
  s16x8 aw[4][2][3];
  #pragma unroll
  for (int mt = 0; mt < 4; ++mt) {
    #pragma unroll
    for (int s = 0; s < 2; ++s) {
      float xv[8];
      #pragma unroll
      for (int e = 0; e < 8; ++e)
        xv[e] = sW2[(32 * s + 8 * h + e) * H + 16 * mt + rl];
      split3(xv, aw[mt][s][0], aw[mt][s][1], aw[mt][s][2]);
    }
  }

  // per-lane f3 / b_f2 along D rows j = 16*mt + 4*h + reg
  f32x4 f3v[4], bf2v[4];
  #pragma unroll
  for (int mt = 0; mt < 4; ++mt) {
    f3v[mt]  = *(const f32x4*)&sF3[16 * mt + 4 * h];
    bf2v[mt] = *(const f32x4*)&sBf2[16 * mt + 4 * h];
  }

  // hoisted f1-row weights at this lane's k slots (48 VGPRs)
  f32x4 wy[2][2], wt1[2][2], wb[2][2];
  #pragma unroll
  for (int s = 0; s < 2; ++s) {
    const int k0 = 32 * s + 8 * h;
    wy[s][0]  = *(const f32x4*)&sF1y[k0]; wy[s][1]  = *(const f32x4*)&sF1y[k0 + 4];
    wt1[s][0] = *(const f32x4*)&sF1t[k0]; wt1[s][1] = *(const f32x4*)&sF1t[k0 + 4];
    wb[s][0]  = *(const f32x4*)&sBF[k0];  wb[s][1]  = *(const f32x4*)&sBF[k0 + 4];
  }

  const float bf3 = b_f3[0];
  const float bg2 = b_g2[0];
  float y  = logf(ip[b]);
  float zz = 0.0f;
  float sb0 = 0.f, sb1 = 0.f, sb2 = 0.f, sb3 = 0.f;   // 4-deep store shift reg

  #pragma unroll 1
  for (int t = 0; t < HOR; ++t) {
    // one threefry per lane per 4 steps: quarter h generates z for step t+h
    if ((t & 3) == 0) {
      const int tk = t + h;
      uint32_t x0 = 0u, x1 = (uint32_t)r;
      tf2x32(sKA[tk], sKB[tk], x0, x1);
      zz = bits_to_normal(x0 ^ x1);
    }
    const float z  = __shfl(zz, rl + 16 * (t & 3));
    const float tt = (float)t;

    // C init = b_f2[j] (folds the bias add into the accumulator)
    f32x4 c[4];
    #pragma unroll
    for (int mt = 0; mt < 4; ++mt) c[mt] = bf2v[mt];

    // ---- B fragments for both s phases (h1 = silu(pre)) ----
    s16x8 bh[2], bm[2], bl[2];
    #pragma unroll
    for (int s = 0; s < 2; ++s) {
      float hv[8];
      #pragma unroll
      for (int d2 = 0; d2 < 2; ++d2) {
        const f32x4 a_ = wy[s][d2], b_ = wt1[s][d2], cc = wb[s][d2];
        hv[4*d2+0] = siluf(fmaf(y, a_.x, fmaf(tt, b_.x, cc.x)));
        hv[4*d2+1] = siluf(fmaf(y, a_.y, fmaf(tt, b_.y, cc.y)));
        hv[4*d2+2] = siluf(fmaf(y, a_.z, fmaf(tt, b_.z, cc.z)));
        hv[4*d2+3] = siluf(fmaf(y, a_.w, fmaf(tt, b_.w, cc.w)));
      }
      split3(hv, bh[s], bm[s], bl[s]);
    }

    // g-net partials: 4 independent 4-deep fma chains (depth ~35cy vs 96)
    float ga0, ga1, ga2, ga3;

    // ---- MFMA s=0 cluster (24), term-major ----
    #pragma unroll
    for (int mt = 0; mt < 4; ++mt) c[mt] = MFMA16(aw[mt][0][0], bh[0], c[mt]); // hh
    #pragma unroll
    for (int mt = 0; mt < 4; ++mt) c[mt] = MFMA16(aw[mt][0][0], bm[0], c[mt]); // hm
    #pragma unroll
    for (int mt = 0; mt < 4; ++mt) c[mt] = MFMA16(aw[mt][0][1], bh[0], c[mt]); // mh
    #pragma unroll
    for (int mt = 0; mt < 4; ++mt) c[mt] = MFMA16(aw[mt][0][1], bm[0], c[mt]); // mm
    #pragma unroll
    for (int mt = 0; mt < 4; ++mt) c[mt] = MFMA16(aw[mt][0][0], bl[0], c[mt]); // hl
    #pragma unroll
    for (int mt = 0; mt < 4; ++mt) c[mt] = MFMA16(aw[mt][0][2], bh[0], c[mt]); // lh

    // ---- g-net phase 0 (k = 8h..8h+7): fills the MFMA shadow ----
    {
      const int k0 = 8 * h;
      const f32x4 gy0 = *(const f32x4*)&sGy[k0], gy1 = *(const f32x4*)&sGy[k0 + 4];
      const f32x4 gt0 = *(const f32x4*)&sGt[k0], gt1 = *(const f32x4*)&sGt[k0 + 4];
      const f32x4 gb0 = *(const f32x4*)&sBG[k0], gb1 = *(const f32x4*)&sBG[k0 + 4];
      const f32x4 g20 = *(const f32x4*)&sG2[k0], g21 = *(const f32x4*)&sG2[k0 + 4];
      ga0 = siluf(fmaf(y, gy0.x, fmaf(tt, gt0.x, gb0.x))) * g20.x;
      ga1 = siluf(fmaf(y, gy0.y, fmaf(tt, gt0.y, gb0.y))) * g20.y;
      ga2 = siluf(fmaf(y, gy0.z, fmaf(tt, gt0.z, gb0.z))) * g20.z;
      ga3 = siluf(fmaf(y, gy0.w, fmaf(tt, gt0.w, gb0.w))) * g20.w;
      ga0 = fmaf(siluf(fmaf(y, gy1.x, fmaf(tt, gt1.x, gb1.x))), g21.x, ga0);
      ga1 = fmaf(siluf(fmaf(y, gy1.y, fmaf(tt, gt1.y, gb1.y))), g21.y, ga1);
      ga2 = fmaf(siluf(fmaf(y, gy1.z, fmaf(tt, gt1.z, gb1.z))), g21.z, ga2);
      ga3 = fmaf(siluf(fmaf(y, gy1.w, fmaf(tt, gt1.w, gb1.w))), g21.w, ga3);
    }

    // ---- MFMA s=1 cluster (24), term-major ----
    #pragma unroll
    for (int mt = 0; mt < 4; ++mt) c[mt] = MFMA16(aw[mt][1][0], bh[1], c[mt]); // hh
    #pragma unroll
    for (int mt = 0; mt < 4; ++mt) c[mt] = MFMA16(aw[mt][1][0], bm[1], c[mt]); // hm
    #pragma unroll
    for (int mt = 0; mt < 4; ++mt) c[mt] = MFMA16(aw[mt][1][1], bh[1], c[mt]); // mh
    #pragma unroll
    for (int mt = 0; mt < 4; ++mt) c[mt] = MFMA16(aw[mt][1][1], bm[1], c[mt]); // mm
    #pragma unroll
    for (int mt = 0; mt < 4; ++mt) c[mt] = MFMA16(aw[mt][1][0], bl[1], c[mt]); // hl
    #pragma unroll
    for (int mt = 0; mt < 4; ++mt) c[mt] = MFMA16(aw[mt][1][2], bh[1], c[mt]); // lh

    // ---- g-net phase 1 (k = 32+8h..): second MFMA shadow ----
    {
      const int k0 = 32 + 8 * h;
      const f32x4 gy0 = *(const f32x4*)&sGy[k0], gy1 = *(const f32x4*)&sGy[k0 + 4];
      const f32x4 gt0 = *(const f32x4*)&sGt[k0], gt1 = *(const f32x4*)&sGt[k0 + 4];
      const f32x4 gb0 = *(const f32x4*)&sBG[k0], gb1 = *(const f32x4*)&sBG[k0 + 4];
      const f32x4 g20 = *(const f32x4*)&sG2[k0], g21 = *(const f32x4*)&sG2[k0 + 4];
      ga0 = fmaf(siluf(fmaf(y, gy0.x, fmaf(tt, gt0.x, gb0.x))), g20.x, ga0);
      ga1 = fmaf(siluf(fmaf(y, gy0.y, fmaf(tt, gt0.y, gb0.y))), g20.y, ga1);
      ga2 = fmaf(siluf(fmaf(y, gy0.z, fmaf(tt, gt0.z, gb0.z))), g20.z, ga2);
      ga3 = fmaf(siluf(fmaf(y, gy0.w, fmaf(tt, gt0.w, gb0.w))), g20.w, ga3);
      ga0 = fmaf(siluf(fmaf(y, gy1.x, fmaf(tt, gt1.x, gb1.x))), g21.x, ga0);
      ga1 = fmaf(siluf(fmaf(y, gy1.y, fmaf(tt, gt1.y, gb1.y))), g21.y, ga1);
      ga2 = fmaf(siluf(fmaf(y, gy1.z, fmaf(tt, gt1.z, gb1.z))), g21.z, ga2);
      ga3 = fmaf(siluf(fmaf(y, gy1.w, fmaf(tt, gt1.w, gb1.w))), g21.w, ga3);
    }
    float ga = (ga0 + ga1) + (ga2 + ga3);
    ga += __shfl_xor(ga, 16);
    ga += __shfl_xor(ga, 32);
    const float gg = softplus_fast(bg2 + ga) + 1e-6f;

    // ---- f-head: 4 independent 4-deep fma chains + tree ----
    float fa0 = siluf(c[0].x) * f3v[0].x;
    float fa1 = siluf(c[1].x) * f3v[1].x;
    float fa2 = siluf(c[2].x) * f3v[2].x;
    float fa3 = siluf(c[3].x) * f3v[3].x;
    fa0 = fmaf(siluf(c[0].y), f3v[0].y, fa0);
    fa1 = fmaf(siluf(c[1].y), f3v[1].y, fa1);
    fa2 = fmaf(siluf(c[2].y), f3v[2].y, fa2);
    fa3 = fmaf(siluf(c[3].y), f3v[3].y, fa3);
    fa0 = fmaf(siluf(c[0].z), f3v[0].z, fa0);
    fa1 = fmaf(siluf(c[1].z), f3v[1].z, fa1);
    fa2 = fmaf(siluf(c[2].z), f3v[2].z, fa2);
    fa3 = fmaf(siluf(c[3].z), f3v[3].z, fa3);
    fa0 = fmaf(siluf(c[0].w), f3v[0].w, fa0);
    fa1 = fmaf(siluf(c[1].w), f3v[1].w, fa1);
    fa2 = fmaf(siluf(c[2].w), f3v[2].w, fa2);
    fa3 = fmaf(siluf(c[3].w), f3v[3].w, fa3);
    float fa = (fa0 + fa1) + (fa2 + fa3);
    fa += __shfl_xor(fa, 16);
    fa += __shfl_xor(fa, 32);

    // Euler-Maruyama step
    y = (y + (bf3 + fa)) + gg * z;
    const float yl = fminf(fmaxf(y, -20.0f), 20.0f);
    const float e  = __expf(yl);
    // lane h owns t in [16m+4h, 16m+4h+3]; shift-register avoids dyn indexing
    if (((t >> 2) & 3) == h) { sb0 = sb1; sb1 = sb2; sb2 = sb3; sb3 = e; }
    if ((t & 15) == 15) {
      f32x4 v; v.x = sb0; v.y = sb1; v.z = sb2; v.w = sb3;
      *(f32x4*)&out[(size_t)r * HOR + (t & ~15) + 4 * h] = v;
    }
  }
}

extern "C" void kernel_launch(void* const* d_in, const int* in_sizes, int n_in,
                              void* d_out, int out_size, void* d_ws, size_t ws_size,
                              hipStream_t stream) {
  const float* h_t   = (const float*)d_in[0];
  const float* ip    = (const float*)d_in[1];
  const float* W_f1  = (const float*)d_in[2];
  const float* b_f1  = (const float*)d_in[3];
  const float* W_f2  = (const float*)d_in[4];
  const float* b_f2  = (const float*)d_in[5];
  const float* W_f3  = (const float*)d_in[6];
  const float* b_f3  = (const float*)d_in[7];
  const float* W_g1  = (const float*)d_in[8];
  const float* b_g1  = (const float*)d_in[9];
  const float* W_g2  = (const float*)d_in[10];
  const float* b_g2  = (const float*)d_in[11];
  const float* W_mu  = (const float*)d_in[12];
  const float* b_mu  = (const float*)d_in[13];
  const float* W_sig = (const float*)d_in[14];
  const float* b_sig = (const float*)d_in[15];
  float* out = (float*)d_out;
  float* ws  = (float*)d_ws;

  hipLaunchKernelGGL(k_pre, dim3(9), dim3(64), 0, stream,
                     h_t, W_f1, b_f1, W_g1, b_g1, W_mu, b_mu, W_sig, b_sig, out, ws);
  hipLaunchKernelGGL(k_sde, dim3(BN / 64), dim3(256), 0, stream,
                     ip, W_f1, W_f2, b_f2, W_f3, b_f3, W_g1, W_g2, b_g2, out, ws);
}

// Round 10
// 492.200 us; speedup vs baseline: 1.1055x; 1.1055x over previous
//
#include <hip/hip_runtime.h>
#include <stdint.h>

#define HOR 128
#define NPATH 4096
#define BATCH 8
#define DM 512
#define H 64
#define BN (BATCH*NPATH)

typedef __attribute__((ext_vector_type(8))) short s16x8;   // 8 bf16 = 4 VGPRs
typedef __attribute__((ext_vector_type(4))) float f32x4;   // MFMA C/D

// ---------------- threefry2x32 (JAX-exact) ----------------
__device__ __forceinline__ uint32_t rotl32(uint32_t x, int r) {
  return (x << r) | (x >> (32 - r));
}

__device__ __forceinline__ void tf2x32(uint32_t k0, uint32_t k1,
                                       uint32_t& x0, uint32_t& x1) {
  uint32_t k2 = k0 ^ k1 ^ 0x1BD11BDAu;
  x0 += k0; x1 += k1;
#define TFR4(a,b,c,d) \
  x0 += x1; x1 = rotl32(x1,a); x1 ^= x0; \
  x0 += x1; x1 = rotl32(x1,b); x1 ^= x0; \
  x0 += x1; x1 = rotl32(x1,c); x1 ^= x0; \
  x0 += x1; x1 = rotl32(x1,d); x1 ^= x0;
  TFR4(13,15,26,6)  x0 += k1; x1 += k2 + 1u;
  TFR4(17,29,16,24) x0 += k2; x1 += k0 + 2u;
  TFR4(13,15,26,6)  x0 += k0; x1 += k1 + 3u;
  TFR4(17,29,16,24) x0 += k1; x1 += k2 + 4u;
  TFR4(13,15,26,6)  x0 += k2; x1 += k0 + 5u;
#undef TFR4
}

// ---------------- math helpers ----------------
__device__ __forceinline__ float rcpf(float x) { return __builtin_amdgcn_rcpf(x); }
__device__ __forceinline__ float siluf(float x) {
  return x * rcpf(1.0f + __expf(-x));
}
__device__ __forceinline__ float softplusf(float x) {     // k_pre only (unchanged)
  return fmaxf(x, 0.0f) + log1pf(__expf(-fabsf(x)));
}
// in-loop softplus: z = e^-|x| in (0,1] -> 1+z in (1,2], v_log ~1ulp there.
__device__ __forceinline__ float softplus_fast(float x) {
  return fmaxf(x, 0.0f) + __logf(1.0f + __expf(-fabsf(x)));
}

__device__ __forceinline__ float bits_to_normal(uint32_t bits) {
  uint32_t fb = (bits >> 9) | 0x3F800000u;
  float f = __uint_as_float(fb) - 1.0f;
  float u = fmaf(f, 2.0f, -0.99999994f);
  u = fmaxf(u, -0.99999994f);
  float w = -log1pf(-u * u);
  float p;
  if (w < 5.0f) {
    w = w - 2.5f;
    p = 2.81022636e-08f;
    p = fmaf(p, w, 3.43273939e-07f);
    p = fmaf(p, w, -3.5233877e-06f);
    p = fmaf(p, w, -4.39150654e-06f);
    p = fmaf(p, w, 0.00021858087f);
    p = fmaf(p, w, -0.00125372503f);
    p = fmaf(p, w, -0.00417768164f);
    p = fmaf(p, w, 0.246640727f);
    p = fmaf(p, w, 1.50140941f);
  } else {
    w = sqrtf(w) - 3.0f;
    p = -0.000200214257f;
    p = fmaf(p, w, 0.000100950558f);
    p = fmaf(p, w, 0.00134934322f);
    p = fmaf(p, w, -0.00367342844f);
    p = fmaf(p, w, 0.00573950773f);
    p = fmaf(p, w, -0.0076224613f);
    p = fmaf(p, w, 0.00943887047f);
    p = fmaf(p, w, 1.00167406f);
    p = fmaf(p, w, 2.83297682f);
  }
  return 1.41421356237f * (p * u);
}

// pack top-16 bits of two fp32 -> one dword of 2 bf16 (truncation round)
__device__ __forceinline__ uint32_t pack_hi16(uint32_t hi_src, uint32_t lo_src) {
  return __builtin_amdgcn_perm(hi_src, lo_src, 0x07060302u);
}

union FragU { uint32_t u[4]; s16x8 v; };

// split 8 fp32 -> 3 bf16x8 fragments: x = hi + mid + lo + O(2^-24 |x|)
__device__ __forceinline__ void split3(const float (&x)[8],
                                       s16x8& fh, s16x8& fm, s16x8& fl) {
  FragU Hh, Mm, Ll;
  #pragma unroll
  for (int d = 0; d < 4; ++d) {
    float x0 = x[2*d], x1 = x[2*d+1];
    uint32_t a0 = __float_as_uint(x0), a1 = __float_as_uint(x1);
    float r10 = x0 - __uint_as_float(a0 & 0xFFFF0000u);
    float r11 = x1 - __uint_as_float(a1 & 0xFFFF0000u);
    uint32_t m0 = __float_as_uint(r10), m1 = __float_as_uint(r11);
    float r20 = r10 - __uint_as_float(m0 & 0xFFFF0000u);
    float r21 = r11 - __uint_as_float(m1 & 0xFFFF0000u);
    Hh.u[d] = pack_hi16(a1, a0);
    Mm.u[d] = pack_hi16(m1, m0);
    Ll.u[d] = pack_hi16(__float_as_uint(r21), __float_as_uint(r20));
  }
  fh = Hh.v; fm = Mm.v; fl = Ll.v;
}

#define MFMA16(A, B, C) __builtin_amdgcn_mfma_f32_16x16x32_bf16((A), (B), (C), 0, 0, 0)

// ws layout (floats): [0,512) base_f1[b][j], [512,1024) base_g1[b][j],
// (u32 view) [1024,1152) keyA[t], [1152,1280) keyB[t]

__global__ void k_pre(const float* __restrict__ h_t,
                      const float* __restrict__ W_f1, const float* __restrict__ b_f1,
                      const float* __restrict__ W_g1, const float* __restrict__ b_g1,
                      const float* __restrict__ W_mu, const float* __restrict__ b_mu,
                      const float* __restrict__ W_sig, const float* __restrict__ b_sig,
                      float* __restrict__ out, float* __restrict__ ws) {
  int j = threadIdx.x;           // 0..63
  int b = blockIdx.x;
  if (b == 8) {
    uint32_t* keyA = (uint32_t*)ws + 1024;
    uint32_t* keyB = (uint32_t*)ws + 1152;
    for (int t = j; t < HOR; t += 64) {
      uint32_t x0 = 0u, x1 = (uint32_t)t;
      tf2x32(0u, 42u, x0, x1);
      keyA[t] = x0; keyB[t] = x1;
    }
    return;
  }
  const float* h = h_t + b * DM;
  float accF = b_f1[j], accG = b_g1[j];
  float pm = 0.0f, ps = 0.0f;
  #pragma unroll 4
  for (int d = 0; d < DM; ++d) {
    float hv = h[d];
    accF = fmaf(hv, W_f1[d * H + j], accF);
    accG = fmaf(hv, W_g1[d * H + j], accG);
  }
  ws[b * H + j] = accF;
  ws[512 + b * H + j] = accG;
  for (int d = j; d < DM; d += 64) {
    pm = fmaf(h[d], W_mu[d], pm);
    ps = fmaf(h[d], W_sig[d], ps);
  }
  #pragma unroll
  for (int off = 32; off > 0; off >>= 1) {
    pm += __shfl_down(pm, off);
    ps += __shfl_down(ps, off);
  }
  if (j == 0) {
    out[BN * HOR + b] = pm + b_mu[0];
    out[BN * HOR + 8 + b] = softplusf(ps + b_sig[0]) + 1e-6f;
  }
}

// -----------------------------------------------------------------------------
// R10 = R8 (455.8us best, clean counters) + ONLY the two serial-tail cuts that
// don't raise register pressure:
//  1. fa/ga as 4 independent 4-deep fma chains + 2-level tree (was 16-deep).
//  2. in-loop softplus via __logf(1+z) (kills log1pf libm serial tail).
// R9 lesson (unbundled here): removing the opaque-kg anti-LICM hack hoisted
// 64 g-weight loads -> spills (FETCH 10.4MB/WRITE 44MB) costing ~+50us; the
// hack is RESTORED and g-net stays after the MFMA block (no interleave).
// MFMA term-major order, RNG, h1/split3: bit-identical to R8.
// Pre-committed fallback: <2% gain -> j-split 1-barrier 4-wave structure.
// -----------------------------------------------------------------------------
__global__ __launch_bounds__(256, 2)
void k_sde(const float* __restrict__ ip,
           const float* __restrict__ W_f1, const float* __restrict__ W_f2,
           const float* __restrict__ b_f2, const float* __restrict__ W_f3,
           const float* __restrict__ b_f3, const float* __restrict__ W_g1,
           const float* __restrict__ W_g2, const float* __restrict__ b_g2,
           float* __restrict__ out, const float* __restrict__ ws) {
  __shared__ __align__(16) float sW2[H * H];          // prologue staging only
  __shared__ __align__(16) float sF1y[H], sF1t[H], sBF[H];
  __shared__ __align__(16) float sGy[H], sGt[H], sBG[H], sG2[H];
  __shared__ __align__(16) float sF3[H], sBf2[H];
  __shared__ uint32_t sKA[HOR], sKB[HOR];

  const int tid  = threadIdx.x;
  const int rblk = blockIdx.x * 64;       // 64 rows per block (4 waves x 16)
  const int b    = rblk >> 12;            // batch: uniform per block

  #pragma unroll
  for (int m = 0; m < 16; ++m) sW2[tid + 256 * m] = W_f2[tid + 256 * m];
  if (tid < 64) {
    sF1y[tid] = W_f1[512 * H + tid];
    sF1t[tid] = W_f1[513 * H + tid];
    sGy[tid]  = W_g1[512 * H + tid];
    sGt[tid]  = W_g1[513 * H + tid];
    sF3[tid]  = W_f3[tid];
    sG2[tid]  = W_g2[tid];
    sBf2[tid] = b_f2[tid];
  } else if (tid < 128) {
    int i = tid - 64;
    sBF[i] = ws[b * H + i];
    sBG[i] = ws[512 + b * H + i];
  } else {
    const uint32_t* kws = (const uint32_t*)ws;
    int t = tid - 128;
    sKA[t] = kws[1024 + t];
    sKB[t] = kws[1152 + t];
  }
  __syncthreads();

  const int l  = tid & 63;
  const int wv = tid >> 6;
  const int rl = l & 15;                  // row-local / D column / B column
  const int h  = l >> 4;                  // k-group quarter
  const int r  = rblk + wv * 16 + rl;     // global row

  // ---- static A fragments: W2^T, 3-way bf16 split (96 VGPRs) ----
  s16x8 aw[4][2][3];
  #pragma unroll
  for (int mt = 0; mt < 4; ++mt) {
    #pragma unroll
    for (int s = 0; s < 2; ++s) {
      float xv[8];
      #pragma unroll
      for (int e = 0; e < 8; ++e)
        xv[e] = sW2[(32 * s + 8 * h + e) * H + 16 * mt + rl];
      split3(xv, aw[mt][s][0], aw[mt][s][1], aw[mt][s][2]);
    }
  }

  // per-lane f3 / b_f2 along D rows j = 16*mt + 4*h + reg
  f32x4 f3v[4], bf2v[4];
  #pragma unroll
  for (int mt = 0; mt < 4; ++mt) {
    f3v[mt]  = *(const f32x4*)&sF3[16 * mt + 4 * h];
    bf2v[mt] = *(const f32x4*)&sBf2[16 * mt + 4 * h];
  }

  // hoisted f1-row weights at this lane's k slots (48 VGPRs)
  f32x4 wy[2][2], wt1[2][2], wb[2][2];
  #pragma unroll
  for (int s = 0; s < 2; ++s) {
    const int k0 = 32 * s + 8 * h;
    wy[s][0]  = *(const f32x4*)&sF1y[k0]; wy[s][1]  = *(const f32x4*)&sF1y[k0 + 4];
    wt1[s][0] = *(const f32x4*)&sF1t[k0]; wt1[s][1] = *(const f32x4*)&sF1t[k0 + 4];
    wb[s][0]  = *(const f32x4*)&sBF[k0];  wb[s][1]  = *(const f32x4*)&sBF[k0 + 4];
  }

  const float bf3 = b_f3[0];
  const float bg2 = b_g2[0];
  float y  = logf(ip[b]);
  float zz = 0.0f;
  float sb0 = 0.f, sb1 = 0.f, sb2 = 0.f, sb3 = 0.f;   // 4-deep store shift reg

  #pragma unroll 1
  for (int t = 0; t < HOR; ++t) {
    // one threefry per lane per 4 steps: quarter h generates z for step t+h
    if ((t & 3) == 0) {
      const int tk = t + h;
      uint32_t x0 = 0u, x1 = (uint32_t)r;
      tf2x32(sKA[tk], sKB[tk], x0, x1);
      zz = bits_to_normal(x0 ^ x1);
    }
    const float z  = __shfl(zz, rl + 16 * (t & 3));
    const float tt = (float)t;

    // C init = b_f2[j] (folds the bias add into the accumulator)
    f32x4 c[4];
    #pragma unroll
    for (int mt = 0; mt < 4; ++mt) c[mt] = bf2v[mt];

    // ---- B fragments for both s phases (h1 = silu(pre)) ----
    s16x8 bh[2], bm[2], bl[2];
    #pragma unroll
    for (int s = 0; s < 2; ++s) {
      float hv[8];
      #pragma unroll
      for (int d2 = 0; d2 < 2; ++d2) {
        const f32x4 a_ = wy[s][d2], b_ = wt1[s][d2], cc = wb[s][d2];
        hv[4*d2+0] = siluf(fmaf(y, a_.x, fmaf(tt, b_.x, cc.x)));
        hv[4*d2+1] = siluf(fmaf(y, a_.y, fmaf(tt, b_.y, cc.y)));
        hv[4*d2+2] = siluf(fmaf(y, a_.z, fmaf(tt, b_.z, cc.z)));
        hv[4*d2+3] = siluf(fmaf(y, a_.w, fmaf(tt, b_.w, cc.w)));
      }
      split3(hv, bh[s], bm[s], bl[s]);
    }

    // ---- 48 MFMAs, term-major: consecutive ops hit different accumulators ----
    #pragma unroll
    for (int s = 0; s < 2; ++s) {
      #pragma unroll
      for (int mt = 0; mt < 4; ++mt) c[mt] = MFMA16(aw[mt][s][0], bh[s], c[mt]); // hh
      #pragma unroll
      for (int mt = 0; mt < 4; ++mt) c[mt] = MFMA16(aw[mt][s][0], bm[s], c[mt]); // hm
      #pragma unroll
      for (int mt = 0; mt < 4; ++mt) c[mt] = MFMA16(aw[mt][s][1], bh[s], c[mt]); // mh
      #pragma unroll
      for (int mt = 0; mt < 4; ++mt) c[mt] = MFMA16(aw[mt][s][1], bm[s], c[mt]); // mm
      #pragma unroll
      for (int mt = 0; mt < 4; ++mt) c[mt] = MFMA16(aw[mt][s][0], bl[s], c[mt]); // hl
      #pragma unroll
      for (int mt = 0; mt < 4; ++mt) c[mt] = MFMA16(aw[mt][s][2], bh[s], c[mt]); // lh
    }

    // g-net from LDS (opaque index blocks LICM from hoisting 64 regs of loads);
    // independent of the MFMA chain -> schedules into its shadow.
    // 4 independent chains: critical path ~96cy -> ~35cy.
    int kg = 8 * h;
    asm volatile("" : "+v"(kg));
    float ga0, ga1, ga2, ga3;
    {
      const int k0 = kg;
      const f32x4 gy0 = *(const f32x4*)&sGy[k0], gy1 = *(const f32x4*)&sGy[k0 + 4];
      const f32x4 gt0 = *(const f32x4*)&sGt[k0], gt1 = *(const f32x4*)&sGt[k0 + 4];
      const f32x4 gb0 = *(const f32x4*)&sBG[k0], gb1 = *(const f32x4*)&sBG[k0 + 4];
      const f32x4 g20 = *(const f32x4*)&sG2[k0], g21 = *(const f32x4*)&sG2[k0 + 4];
      ga0 = siluf(fmaf(y, gy0.x, fmaf(tt, gt0.x, gb0.x))) * g20.x;
      ga1 = siluf(fmaf(y, gy0.y, fmaf(tt, gt0.y, gb0.y))) * g20.y;
      ga2 = siluf(fmaf(y, gy0.z, fmaf(tt, gt0.z, gb0.z))) * g20.z;
      ga3 = siluf(fmaf(y, gy0.w, fmaf(tt, gt0.w, gb0.w))) * g20.w;
      ga0 = fmaf(siluf(fmaf(y, gy1.x, fmaf(tt, gt1.x, gb1.x))), g21.x, ga0);
      ga1 = fmaf(siluf(fmaf(y, gy1.y, fmaf(tt, gt1.y, gb1.y))), g21.y, ga1);
      ga2 = fmaf(siluf(fmaf(y, gy1.z, fmaf(tt, gt1.z, gb1.z))), g21.z, ga2);
      ga3 = fmaf(siluf(fmaf(y, gy1.w, fmaf(tt, gt1.w, gb1.w))), g21.w, ga3);
    }
    {
      const int k0 = kg + 32;
      const f32x4 gy0 = *(const f32x4*)&sGy[k0], gy1 = *(const f32x4*)&sGy[k0 + 4];
      const f32x4 gt0 = *(const f32x4*)&sGt[k0], gt1 = *(const f32x4*)&sGt[k0 + 4];
      const f32x4 gb0 = *(const f32x4*)&sBG[k0], gb1 = *(const f32x4*)&sBG[k0 + 4];
      const f32x4 g20 = *(const f32x4*)&sG2[k0], g21 = *(const f32x4*)&sG2[k0 + 4];
      ga0 = fmaf(siluf(fmaf(y, gy0.x, fmaf(tt, gt0.x, gb0.x))), g20.x, ga0);
      ga1 = fmaf(siluf(fmaf(y, gy0.y, fmaf(tt, gt0.y, gb0.y))), g20.y, ga1);
      ga2 = fmaf(siluf(fmaf(y, gy0.z, fmaf(tt, gt0.z, gb0.z))), g20.z, ga2);
      ga3 = fmaf(siluf(fmaf(y, gy0.w, fmaf(tt, gt0.w, gb0.w))), g20.w, ga3);
      ga0 = fmaf(siluf(fmaf(y, gy1.x, fmaf(tt, gt1.x, gb1.x))), g21.x, ga0);
      ga1 = fmaf(siluf(fmaf(y, gy1.y, fmaf(tt, gt1.y, gb1.y))), g21.y, ga1);
      ga2 = fmaf(siluf(fmaf(y, gy1.z, fmaf(tt, gt1.z, gb1.z))), g21.z, ga2);
      ga3 = fmaf(siluf(fmaf(y, gy1.w, fmaf(tt, gt1.w, gb1.w))), g21.w, ga3);
    }
    float ga = (ga0 + ga1) + (ga2 + ga3);
    ga += __shfl_xor(ga, 16);
    ga += __shfl_xor(ga, 32);
    const float gg = softplus_fast(bg2 + ga) + 1e-6f;

    // ---- f-head: 4 independent 4-deep fma chains + tree ----
    float fa0 = siluf(c[0].x) * f3v[0].x;
    float fa1 = siluf(c[1].x) * f3v[1].x;
    float fa2 = siluf(c[2].x) * f3v[2].x;
    float fa3 = siluf(c[3].x) * f3v[3].x;
    fa0 = fmaf(siluf(c[0].y), f3v[0].y, fa0);
    fa1 = fmaf(siluf(c[1].y), f3v[1].y, fa1);
    fa2 = fmaf(siluf(c[2].y), f3v[2].y, fa2);
    fa3 = fmaf(siluf(c[3].y), f3v[3].y, fa3);
    fa0 = fmaf(siluf(c[0].z), f3v[0].z, fa0);
    fa1 = fmaf(siluf(c[1].z), f3v[1].z, fa1);
    fa2 = fmaf(siluf(c[2].z), f3v[2].z, fa2);
    fa3 = fmaf(siluf(c[3].z), f3v[3].z, fa3);
    fa0 = fmaf(siluf(c[0].w), f3v[0].w, fa0);
    fa1 = fmaf(siluf(c[1].w), f3v[1].w, fa1);
    fa2 = fmaf(siluf(c[2].w), f3v[2].w, fa2);
    fa3 = fmaf(siluf(c[3].w), f3v[3].w, fa3);
    float fa = (fa0 + fa1) + (fa2 + fa3);
    fa += __shfl_xor(fa, 16);
    fa += __shfl_xor(fa, 32);

    // Euler-Maruyama step
    y = (y + (bf3 + fa)) + gg * z;
    const float yl = fminf(fmaxf(y, -20.0f), 20.0f);
    const float e  = __expf(yl);
    // lane h owns t in [16m+4h, 16m+4h+3]; shift-register avoids dyn indexing
    if (((t >> 2) & 3) == h) { sb0 = sb1; sb1 = sb2; sb2 = sb3; sb3 = e; }
    if ((t & 15) == 15) {
      f32x4 v; v.x = sb0; v.y = sb1; v.z = sb2; v.w = sb3;
      *(f32x4*)&out[(size_t)r * HOR + (t & ~15) + 4 * h] = v;
    }
  }
}

extern "C" void kernel_launch(void* const* d_in, const int* in_sizes, int n_in,
                              void* d_out, int out_size, void* d_ws, size_t ws_size,
                              hipStream_t stream) {
  const float* h_t   = (const float*)d_in[0];
  const float* ip    = (const float*)d_in[1];
  const float* W_f1  = (const float*)d_in[2];
  const float* b_f1  = (const float*)d_in[3];
  const float* W_f2  = (const float*)d_in[4];
  const float* b_f2  = (const float*)d_in[5];
  const float* W_f3  = (const float*)d_in[6];
  const float* b_f3  = (const float*)d_in[7];
  const float* W_g1  = (const float*)d_in[8];
  const float* b_g1  = (const float*)d_in[9];
  const float* W_g2  = (const float*)d_in[10];
  const float* b_g2  = (const float*)d_in[11];
  const float* W_mu  = (const float*)d_in[12];
  const float* b_mu  = (const float*)d_in[13];
  const float* W_sig = (const float*)d_in[14];
  const float* b_sig = (const float*)d_in[15];
  float* out = (float*)d_out;
  float* ws  = (float*)d_ws;

  hipLaunchKernelGGL(k_pre, dim3(9), dim3(64), 0, stream,
                     h_t, W_f1, b_f1, W_g1, b_g1, W_mu, b_mu, W_sig, b_sig, out, ws);
  hipLaunchKernelGGL(k_sde, dim3(BN / 64), dim3(256), 0, stream,
                     ip, W_f1, W_f2, b_f2, W_f3, b_f3, W_g1, W_g2, b_g2, out, ws);
}

// Round 11
// 488.686 us; speedup vs baseline: 1.1135x; 1.0072x over previous
//
#include <hip/hip_runtime.h>
#include <stdint.h>

#define HOR 128
#define NPATH 4096
#define BATCH 8
#define DM 512
#define H 64
#define BN (BATCH*NPATH)

typedef __attribute__((ext_vector_type(8))) short s16x8;   // 8 bf16 = 4 VGPRs
typedef __attribute__((ext_vector_type(4))) float f32x4;   // MFMA C/D

// ---------------- threefry2x32 (JAX-exact) ----------------
__device__ __forceinline__ uint32_t rotl32(uint32_t x, int r) {
  return (x << r) | (x >> (32 - r));
}

__device__ __forceinline__ void tf2x32(uint32_t k0, uint32_t k1,
                                       uint32_t& x0, uint32_t& x1) {
  uint32_t k2 = k0 ^ k1 ^ 0x1BD11BDAu;
  x0 += k0; x1 += k1;
#define TFR4(a,b,c,d) \
  x0 += x1; x1 = rotl32(x1,a); x1 ^= x0; \
  x0 += x1; x1 = rotl32(x1,b); x1 ^= x0; \
  x0 += x1; x1 = rotl32(x1,c); x1 ^= x0; \
  x0 += x1; x1 = rotl32(x1,d); x1 ^= x0;
  TFR4(13,15,26,6)  x0 += k1; x1 += k2 + 1u;
  TFR4(17,29,16,24) x0 += k2; x1 += k0 + 2u;
  TFR4(13,15,26,6)  x0 += k0; x1 += k1 + 3u;
  TFR4(17,29,16,24) x0 += k1; x1 += k2 + 4u;
  TFR4(13,15,26,6)  x0 += k2; x1 += k0 + 5u;
#undef TFR4
}

// ---------------- math helpers ----------------
__device__ __forceinline__ float rcpf(float x) { return __builtin_amdgcn_rcpf(x); }
__device__ __forceinline__ float siluf(float x) {
  return x * rcpf(1.0f + __expf(-x));
}
__device__ __forceinline__ float softplusf(float x) {     // k_pre only (unchanged)
  return fmaxf(x, 0.0f) + log1pf(__expf(-fabsf(x)));
}
// in-loop softplus: z = e^-|x| in (0,1] -> 1+z in (1,2], v_log ~1ulp there.
__device__ __forceinline__ float softplus_fast(float x) {
  return fmaxf(x, 0.0f) + __logf(1.0f + __expf(-fabsf(x)));
}

__device__ __forceinline__ float bits_to_normal(uint32_t bits) {
  uint32_t fb = (bits >> 9) | 0x3F800000u;
  float f = __uint_as_float(fb) - 1.0f;
  float u = fmaf(f, 2.0f, -0.99999994f);
  u = fmaxf(u, -0.99999994f);
  float w = -log1pf(-u * u);
  float p;
  if (w < 5.0f) {
    w = w - 2.5f;
    p = 2.81022636e-08f;
    p = fmaf(p, w, 3.43273939e-07f);
    p = fmaf(p, w, -3.5233877e-06f);
    p = fmaf(p, w, -4.39150654e-06f);
    p = fmaf(p, w, 0.00021858087f);
    p = fmaf(p, w, -0.00125372503f);
    p = fmaf(p, w, -0.00417768164f);
    p = fmaf(p, w, 0.246640727f);
    p = fmaf(p, w, 1.50140941f);
  } else {
    w = sqrtf(w) - 3.0f;
    p = -0.000200214257f;
    p = fmaf(p, w, 0.000100950558f);
    p = fmaf(p, w, 0.00134934322f);
    p = fmaf(p, w, -0.00367342844f);
    p = fmaf(p, w, 0.00573950773f);
    p = fmaf(p, w, -0.0076224613f);
    p = fmaf(p, w, 0.00943887047f);
    p = fmaf(p, w, 1.00167406f);
    p = fmaf(p, w, 2.83297682f);
  }
  return 1.41421356237f * (p * u);
}

// pack top-16 bits of two fp32 -> one dword of 2 bf16 (truncation round)
__device__ __forceinline__ uint32_t pack_hi16(uint32_t hi_src, uint32_t lo_src) {
  return __builtin_amdgcn_perm(hi_src, lo_src, 0x07060302u);
}

union FragU { uint32_t u[4]; s16x8 v; };

// split 8 fp32 -> 3 bf16x8 fragments: x = hi + mid + lo + O(2^-24 |x|)
__device__ __forceinline__ void split3(const float (&x)[8],
                                       s16x8& fh, s16x8& fm, s16x8& fl) {
  FragU Hh, Mm, Ll;
  #pragma unroll
  for (int d = 0; d < 4; ++d) {
    float x0 = x[2*d], x1 = x[2*d+1];
    uint32_t a0 = __float_as_uint(x0), a1 = __float_as_uint(x1);
    float r10 = x0 - __uint_as_float(a0 & 0xFFFF0000u);
    float r11 = x1 - __uint_as_float(a1 & 0xFFFF0000u);
    uint32_t m0 = __float_as_uint(r10), m1 = __float_as_uint(r11);
    float r20 = r10 - __uint_as_float(m0 & 0xFFFF0000u);
    float r21 = r11 - __uint_as_float(m1 & 0xFFFF0000u);
    Hh.u[d] = pack_hi16(a1, a0);
    Mm.u[d] = pack_hi16(m1, m0);
    Ll.u[d] = pack_hi16(__float_as_uint(r21), __float_as_uint(r20));
  }
  fh = Hh.v; fm = Mm.v; fl = Ll.v;
}

#define MFMA16(A, B, C) __builtin_amdgcn_mfma_f32_16x16x32_bf16((A), (B), (C), 0, 0, 0)

// ws layout (floats): [0,512) base_f1[b][j], [512,1024) base_g1[b][j],
// (u32 view) [1024,1152) keyA[t], [1152,1280) keyB[t]

__global__ void k_pre(const float* __restrict__ h_t,
                      const float* __restrict__ W_f1, const float* __restrict__ b_f1,
                      const float* __restrict__ W_g1, const float* __restrict__ b_g1,
                      const float* __restrict__ W_mu, const float* __restrict__ b_mu,
                      const float* __restrict__ W_sig, const float* __restrict__ b_sig,
                      float* __restrict__ out, float* __restrict__ ws) {
  int j = threadIdx.x;           // 0..63
  int b = blockIdx.x;
  if (b == 8) {
    uint32_t* keyA = (uint32_t*)ws + 1024;
    uint32_t* keyB = (uint32_t*)ws + 1152;
    for (int t = j; t < HOR; t += 64) {
      uint32_t x0 = 0u, x1 = (uint32_t)t;
      tf2x32(0u, 42u, x0, x1);
      keyA[t] = x0; keyB[t] = x1;
    }
    return;
  }
  const float* h = h_t + b * DM;
  float accF = b_f1[j], accG = b_g1[j];
  float pm = 0.0f, ps = 0.0f;
  #pragma unroll 4
  for (int d = 0; d < DM; ++d) {
    float hv = h[d];
    accF = fmaf(hv, W_f1[d * H + j], accF);
    accG = fmaf(hv, W_g1[d * H + j], accG);
  }
  ws[b * H + j] = accF;
  ws[512 + b * H + j] = accG;
  for (int d = j; d < DM; d += 64) {
    pm = fmaf(h[d], W_mu[d], pm);
    ps = fmaf(h[d], W_sig[d], ps);
  }
  #pragma unroll
  for (int off = 32; off > 0; off >>= 1) {
    pm += __shfl_down(pm, off);
    ps += __shfl_down(ps, off);
  }
  if (j == 0) {
    out[BN * HOR + b] = pm + b_mu[0];
    out[BN * HOR + 8 + b] = softplusf(ps + b_sig[0]) + 1e-6f;
  }
}

// -----------------------------------------------------------------------------
// R11 = R10 (419.7us best, clean counters) + reduction-tail restructure:
//  1. fa/ga butterfly: 3 PARALLEL shfl_xor(16/32/48) + tree add, replacing
//     2 SERIAL shfl_xor(16 then 32). Same sum, same order:
//     old final = (x+x16) + (x32+x48); new = (x+x16) + (x32+x48). One DS
//     round-trip (~120cy) instead of two serial per reduction.
//  2. Issue-order overlap: ga shuffles issued -> f-head VALU chains run under
//     ga's DS latency -> fa shuffles issued -> softplus(ga) under fa latency.
// Everything else identical to R10 (term-major MFMA, opaque-kg anti-LICM,
// tree-reduced chains, fast softplus). No register-pressure change.
// -----------------------------------------------------------------------------
__global__ __launch_bounds__(256, 2)
void k_sde(const float* __restrict__ ip,
           const float* __restrict__ W_f1, const float* __restrict__ W_f2,
           const float* __restrict__ b_f2, const float* __restrict__ W_f3,
           const float* __restrict__ b_f3, const float* __restrict__ W_g1,
           const float* __restrict__ W_g2, const float* __restrict__ b_g2,
           float* __restrict__ out, const float* __restrict__ ws) {
  __shared__ __align__(16) float sW2[H * H];          // prologue staging only
  __shared__ __align__(16) float sF1y[H], sF1t[H], sBF[H];
  __shared__ __align__(16) float sGy[H], sGt[H], sBG[H], sG2[H];
  __shared__ __align__(16) float sF3[H], sBf2[H];
  __shared__ uint32_t sKA[HOR], sKB[HOR];

  const int tid  = threadIdx.x;
  const int rblk = blockIdx.x * 64;       // 64 rows per block (4 waves x 16)
  const int b    = rblk >> 12;            // batch: uniform per block

  #pragma unroll
  for (int m = 0; m < 16; ++m) sW2[tid + 256 * m] = W_f2[tid + 256 * m];
  if (tid < 64) {
    sF1y[tid] = W_f1[512 * H + tid];
    sF1t[tid] = W_f1[513 * H + tid];
    sGy[tid]  = W_g1[512 * H + tid];
    sGt[tid]  = W_g1[513 * H + tid];
    sF3[tid]  = W_f3[tid];
    sG2[tid]  = W_g2[tid];
    sBf2[tid] = b_f2[tid];
  } else if (tid < 128) {
    int i = tid - 64;
    sBF[i] = ws[b * H + i];
    sBG[i] = ws[512 + b * H + i];
  } else {
    const uint32_t* kws = (const uint32_t*)ws;
    int t = tid - 128;
    sKA[t] = kws[1024 + t];
    sKB[t] = kws[1152 + t];
  }
  __syncthreads();

  const int l  = tid & 63;
  const int wv = tid >> 6;
  const int rl = l & 15;                  // row-local / D column / B column
  const int h  = l >> 4;                  // k-group quarter
  const int r  = rblk + wv * 16 + rl;     // global row

  // ---- static A fragments: W2^T, 3-way bf16 split (96 VGPRs) ----
  s16x8 aw[4][2][3];
  #pragma unroll
  for (int mt = 0; mt < 4; ++mt) {
    #pragma unroll
    for (int s = 0; s < 2; ++s) {
      float xv[8];
      #pragma unroll
      for (int e = 0; e < 8; ++e)
        xv[e] = sW2[(32 * s + 8 * h + e) * H + 16 * mt + rl];
      split3(xv, aw[mt][s][0], aw[mt][s][1], aw[mt][s][2]);
    }
  }

  // per-lane f3 / b_f2 along D rows j = 16*mt + 4*h + reg
  f32x4 f3v[4], bf2v[4];
  #pragma unroll
  for (int mt = 0; mt < 4; ++mt) {
    f3v[mt]  = *(const f32x4*)&sF3[16 * mt + 4 * h];
    bf2v[mt] = *(const f32x4*)&sBf2[16 * mt + 4 * h];
  }

  // hoisted f1-row weights at this lane's k slots (48 VGPRs)
  f32x4 wy[2][2], wt1[2][2], wb[2][2];
  #pragma unroll
  for (int s = 0; s < 2; ++s) {
    const int k0 = 32 * s + 8 * h;
    wy[s][0]  = *(const f32x4*)&sF1y[k0]; wy[s][1]  = *(const f32x4*)&sF1y[k0 + 4];
    wt1[s][0] = *(const f32x4*)&sF1t[k0]; wt1[s][1] = *(const f32x4*)&sF1t[k0 + 4];
    wb[s][0]  = *(const f32x4*)&sBF[k0];  wb[s][1]  = *(const f32x4*)&sBF[k0 + 4];
  }

  const float bf3 = b_f3[0];
  const float bg2 = b_g2[0];
  float y  = logf(ip[b]);
  float zz = 0.0f;
  float sb0 = 0.f, sb1 = 0.f, sb2 = 0.f, sb3 = 0.f;   // 4-deep store shift reg

  #pragma unroll 1
  for (int t = 0; t < HOR; ++t) {
    // one threefry per lane per 4 steps: quarter h generates z for step t+h
    if ((t & 3) == 0) {
      const int tk = t + h;
      uint32_t x0 = 0u, x1 = (uint32_t)r;
      tf2x32(sKA[tk], sKB[tk], x0, x1);
      zz = bits_to_normal(x0 ^ x1);
    }
    const float z  = __shfl(zz, rl + 16 * (t & 3));
    const float tt = (float)t;

    // C init = b_f2[j] (folds the bias add into the accumulator)
    f32x4 c[4];
    #pragma unroll
    for (int mt = 0; mt < 4; ++mt) c[mt] = bf2v[mt];

    // ---- B fragments for both s phases (h1 = silu(pre)) ----
    s16x8 bh[2], bm[2], bl[2];
    #pragma unroll
    for (int s = 0; s < 2; ++s) {
      float hv[8];
      #pragma unroll
      for (int d2 = 0; d2 < 2; ++d2) {
        const f32x4 a_ = wy[s][d2], b_ = wt1[s][d2], cc = wb[s][d2];
        hv[4*d2+0] = siluf(fmaf(y, a_.x, fmaf(tt, b_.x, cc.x)));
        hv[4*d2+1] = siluf(fmaf(y, a_.y, fmaf(tt, b_.y, cc.y)));
        hv[4*d2+2] = siluf(fmaf(y, a_.z, fmaf(tt, b_.z, cc.z)));
        hv[4*d2+3] = siluf(fmaf(y, a_.w, fmaf(tt, b_.w, cc.w)));
      }
      split3(hv, bh[s], bm[s], bl[s]);
    }

    // ---- 48 MFMAs, term-major: consecutive ops hit different accumulators ----
    #pragma unroll
    for (int s = 0; s < 2; ++s) {
      #pragma unroll
      for (int mt = 0; mt < 4; ++mt) c[mt] = MFMA16(aw[mt][s][0], bh[s], c[mt]); // hh
      #pragma unroll
      for (int mt = 0; mt < 4; ++mt) c[mt] = MFMA16(aw[mt][s][0], bm[s], c[mt]); // hm
      #pragma unroll
      for (int mt = 0; mt < 4; ++mt) c[mt] = MFMA16(aw[mt][s][1], bh[s], c[mt]); // mh
      #pragma unroll
      for (int mt = 0; mt < 4; ++mt) c[mt] = MFMA16(aw[mt][s][1], bm[s], c[mt]); // mm
      #pragma unroll
      for (int mt = 0; mt < 4; ++mt) c[mt] = MFMA16(aw[mt][s][0], bl[s], c[mt]); // hl
      #pragma unroll
      for (int mt = 0; mt < 4; ++mt) c[mt] = MFMA16(aw[mt][s][2], bh[s], c[mt]); // lh
    }

    // g-net from LDS (opaque index blocks LICM from hoisting 64 regs of loads);
    // independent of the MFMA chain -> schedules into its shadow.
    int kg = 8 * h;
    asm volatile("" : "+v"(kg));
    float ga0, ga1, ga2, ga3;
    {
      const int k0 = kg;
      const f32x4 gy0 = *(const f32x4*)&sGy[k0], gy1 = *(const f32x4*)&sGy[k0 + 4];
      const f32x4 gt0 = *(const f32x4*)&sGt[k0], gt1 = *(const f32x4*)&sGt[k0 + 4];
      const f32x4 gb0 = *(const f32x4*)&sBG[k0], gb1 = *(const f32x4*)&sBG[k0 + 4];
      const f32x4 g20 = *(const f32x4*)&sG2[k0], g21 = *(const f32x4*)&sG2[k0 + 4];
      ga0 = siluf(fmaf(y, gy0.x, fmaf(tt, gt0.x, gb0.x))) * g20.x;
      ga1 = siluf(fmaf(y, gy0.y, fmaf(tt, gt0.y, gb0.y))) * g20.y;
      ga2 = siluf(fmaf(y, gy0.z, fmaf(tt, gt0.z, gb0.z))) * g20.z;
      ga3 = siluf(fmaf(y, gy0.w, fmaf(tt, gt0.w, gb0.w))) * g20.w;
      ga0 = fmaf(siluf(fmaf(y, gy1.x, fmaf(tt, gt1.x, gb1.x))), g21.x, ga0);
      ga1 = fmaf(siluf(fmaf(y, gy1.y, fmaf(tt, gt1.y, gb1.y))), g21.y, ga1);
      ga2 = fmaf(siluf(fmaf(y, gy1.z, fmaf(tt, gt1.z, gb1.z))), g21.z, ga2);
      ga3 = fmaf(siluf(fmaf(y, gy1.w, fmaf(tt, gt1.w, gb1.w))), g21.w, ga3);
    }
    {
      const int k0 = kg + 32;
      const f32x4 gy0 = *(const f32x4*)&sGy[k0], gy1 = *(const f32x4*)&sGy[k0 + 4];
      const f32x4 gt0 = *(const f32x4*)&sGt[k0], gt1 = *(const f32x4*)&sGt[k0 + 4];
      const f32x4 gb0 = *(const f32x4*)&sBG[k0], gb1 = *(const f32x4*)&sBG[k0 + 4];
      const f32x4 g20 = *(const f32x4*)&sG2[k0], g21 = *(const f32x4*)&sG2[k0 + 4];
      ga0 = fmaf(siluf(fmaf(y, gy0.x, fmaf(tt, gt0.x, gb0.x))), g20.x, ga0);
      ga1 = fmaf(siluf(fmaf(y, gy0.y, fmaf(tt, gt0.y, gb0.y))), g20.y, ga1);
      ga2 = fmaf(siluf(fmaf(y, gy0.z, fmaf(tt, gt0.z, gb0.z))), g20.z, ga2);
      ga3 = fmaf(siluf(fmaf(y, gy0.w, fmaf(tt, gt0.w, gb0.w))), g20.w, ga3);
      ga0 = fmaf(siluf(fmaf(y, gy1.x, fmaf(tt, gt1.x, gb1.x))), g21.x, ga0);
      ga1 = fmaf(siluf(fmaf(y, gy1.y, fmaf(tt, gt1.y, gb1.y))), g21.y, ga1);
      ga2 = fmaf(siluf(fmaf(y, gy1.z, fmaf(tt, gt1.z, gb1.z))), g21.z, ga2);
      ga3 = fmaf(siluf(fmaf(y, gy1.w, fmaf(tt, gt1.w, gb1.w))), g21.w, ga3);
    }
    const float ga = (ga0 + ga1) + (ga2 + ga3);
    // ga butterfly: 3 parallel fetches (one DS round-trip, not two serial)
    const float gaA = __shfl_xor(ga, 16);
    const float gaB = __shfl_xor(ga, 32);
    const float gaC = __shfl_xor(ga, 48);

    // ---- f-head VALU chains run under ga's DS latency ----
    float fa0 = siluf(c[0].x) * f3v[0].x;
    float fa1 = siluf(c[1].x) * f3v[1].x;
    float fa2 = siluf(c[2].x) * f3v[2].x;
    float fa3 = siluf(c[3].x) * f3v[3].x;
    fa0 = fmaf(siluf(c[0].y), f3v[0].y, fa0);
    fa1 = fmaf(siluf(c[1].y), f3v[1].y, fa1);
    fa2 = fmaf(siluf(c[2].y), f3v[2].y, fa2);
    fa3 = fmaf(siluf(c[3].y), f3v[3].y, fa3);
    fa0 = fmaf(siluf(c[0].z), f3v[0].z, fa0);
    fa1 = fmaf(siluf(c[1].z), f3v[1].z, fa1);
    fa2 = fmaf(siluf(c[2].z), f3v[2].z, fa2);
    fa3 = fmaf(siluf(c[3].z), f3v[3].z, fa3);
    fa0 = fmaf(siluf(c[0].w), f3v[0].w, fa0);
    fa1 = fmaf(siluf(c[1].w), f3v[1].w, fa1);
    fa2 = fmaf(siluf(c[2].w), f3v[2].w, fa2);
    fa3 = fmaf(siluf(c[3].w), f3v[3].w, fa3);
    const float fa = (fa0 + fa1) + (fa2 + fa3);
    // fa butterfly issued before ga is consumed (overlaps softplus below)
    const float faA = __shfl_xor(fa, 16);
    const float faB = __shfl_xor(fa, 32);
    const float faC = __shfl_xor(fa, 48);

    // consume ga (softplus runs under fa's DS latency)
    const float gaT = (ga + gaA) + (gaB + gaC);
    const float gg  = softplus_fast(bg2 + gaT) + 1e-6f;
    const float faT = (fa + faA) + (faB + faC);

    // Euler-Maruyama step
    y = (y + (bf3 + faT)) + gg * z;
    const float yl = fminf(fmaxf(y, -20.0f), 20.0f);
    const float e  = __expf(yl);
    // lane h owns t in [16m+4h, 16m+4h+3]; shift-register avoids dyn indexing
    if (((t >> 2) & 3) == h) { sb0 = sb1; sb1 = sb2; sb2 = sb3; sb3 = e; }
    if ((t & 15) == 15) {
      f32x4 v; v.x = sb0; v.y = sb1; v.z = sb2; v.w = sb3;
      *(f32x4*)&out[(size_t)r * HOR + (t & ~15) + 4 * h] = v;
    }
  }
}

extern "C" void kernel_launch(void* const* d_in, const int* in_sizes, int n_in,
                              void* d_out, int out_size, void* d_ws, size_t ws_size,
                              hipStream_t stream) {
  const float* h_t   = (const float*)d_in[0];
  const float* ip    = (const float*)d_in[1];
  const float* W_f1  = (const float*)d_in[2];
  const float* b_f1  = (const float*)d_in[3];
  const float* W_f2  = (const float*)d_in[4];
  const float* b_f2  = (const float*)d_in[5];
  const float* W_f3  = (const float*)d_in[6];
  const float* b_f3  = (const float*)d_in[7];
  const float* W_g1  = (const float*)d_in[8];
  const float* b_g1  = (const float*)d_in[9];
  const float* W_g2  = (const float*)d_in[10];
  const float* b_g2  = (const float*)d_in[11];
  const float* W_mu  = (const float*)d_in[12];
  const float* b_mu  = (const float*)d_in[13];
  const float* W_sig = (const float*)d_in[14];
  const float* b_sig = (const float*)d_in[15];
  float* out = (float*)d_out;
  float* ws  = (float*)d_ws;

  hipLaunchKernelGGL(k_pre, dim3(9), dim3(64), 0, stream,
                     h_t, W_f1, b_f1, W_g1, b_g1, W_mu, b_mu, W_sig, b_sig, out, ws);
  hipLaunchKernelGGL(k_sde, dim3(BN / 64), dim3(256), 0, stream,
                     ip, W_f1, W_f2, b_f2, W_f3, b_f3, W_g1, W_g2, b_g2, out, ws);
}